// Round 14
// baseline (1066.053 us; speedup 1.0000x reference)
//
#include <hip/hip_runtime.h>
#include <hip/hip_bf16.h>

#define NEG_SLOPE 0.2f
#define BN_EPS 1e-5f
#define BSHIFT 8            // bucket = 256 dst nodes

__device__ __forceinline__ float lrelu(float x) { return x > 0.f ? x : NEG_SLOPE * x; }
__device__ __forceinline__ float bflo(unsigned u) { return __uint_as_float(u << 16); }
__device__ __forceinline__ float bfhi(unsigned u) { return __uint_as_float(u & 0xffff0000u); }

// ---------- kernel A: hb(bf16) = x@W^T (LDS W, reg-blocked), aS/aD, LDS bucket-hist ----------
__global__ void __launch_bounds__(256, 4) k_gemm_h(
    const float* __restrict__ x, const float* __restrict__ W,
    const float* __restrict__ att_src, const float* __restrict__ att_dst,
    const int* __restrict__ ei, __hip_bfloat16* __restrict__ hb,
    float* __restrict__ aS, float* __restrict__ aD,
    int* __restrict__ bucketCnt, float* __restrict__ bnzero, int N, int E, int NB)
{
    __shared__ float4 xs[64][17];    // x tile
    __shared__ float4 Ws4[64][17];   // Ws4[c][k4] = W row c
    __shared__ int bh[512];
    const int t = threadIdx.x;
    const int c = t & 63;
    const int wv = t >> 6;
    const int n0 = blockIdx.x * 64;

    const float4* Wp = (const float4*)W;
    const float4* xp = (const float4*)x;
    #pragma unroll
    for (int i = 0; i < 4; ++i) {
        int idx = i * 256 + t;               // 0..1023
        Ws4[idx >> 4][idx & 15] = Wp[idx];
        int row = idx >> 4, k4 = idx & 15;
        xs[row][k4] = (n0 + row < N) ? xp[(size_t)n0 * 16 + idx] : make_float4(0,0,0,0);
    }
    for (int i = t; i < NB; i += 256) bh[i] = 0;
    __syncthreads();

    // register-blocked GEMM: lane c = channel, 16 nodes per wave
    float acc[16];
    #pragma unroll
    for (int i = 0; i < 16; ++i) acc[i] = 0.f;
    #pragma unroll
    for (int k4 = 0; k4 < 16; ++k4) {
        float4 w4 = Ws4[c][k4];              // 17-pad: balanced b128 banks
        #pragma unroll
        for (int i = 0; i < 16; ++i) {
            float4 x4 = xs[wv * 16 + i][k4]; // wave-broadcast
            acc[i] = fmaf(x4.x, w4.x, acc[i]);
            acc[i] = fmaf(x4.y, w4.y, acc[i]);
            acc[i] = fmaf(x4.z, w4.z, acc[i]);
            acc[i] = fmaf(x4.w, w4.w, acc[i]);
        }
    }
    const float asc = att_src[c], adc = att_dst[c];
    #pragma unroll
    for (int i = 0; i < 16; ++i) {
        int n = n0 + wv * 16 + i;
        if (n >= N) break;
        float a = acc[i];
        hb[(size_t)n * 64 + c] = __float2bfloat16(a);
        float s = a * asc, d = a * adc;
        #pragma unroll
        for (int off = 32; off; off >>= 1) { s += __shfl_xor(s, off); d += __shfl_xor(d, off); }
        if (c == 0) { aS[n] = s; aD[n] = d; }
    }
    // bucket histogram (LDS-privatized; one global atomic per block,bucket)
    int per = (E + gridDim.x - 1) / gridDim.x;
    int e0 = blockIdx.x * per;
    int e1 = min(e0 + per, E);
    for (int e = e0 + t; e < e1; e += 256) atomicAdd(&bh[ei[E + e] >> BSHIFT], 1);
    __syncthreads();
    for (int i = t; i < NB; i += 256) if (bh[i]) atomicAdd(&bucketCnt[i], bh[i]);
    if (blockIdx.x == 0 && t < 128) bnzero[t] = 0.f;
}

// ---------- bucket scan (391 values, one block) ----------
__global__ void k_bscan(const int* __restrict__ bucketCnt, int* __restrict__ bcur,
                        int* __restrict__ bbase0, int NB, int E)
{
    __shared__ int sh[512];
    const int t = threadIdx.x;
    int v = (t < NB) ? bucketCnt[t] : 0;
    sh[t] = v;
    __syncthreads();
    for (int off = 1; off < 512; off <<= 1) {
        int y = (t >= off) ? sh[t - off] : 0;
        __syncthreads();
        sh[t] += y;
        __syncthreads();
    }
    if (t < NB) { int ex = sh[t] - v; bcur[t] = ex; bbase0[t] = ex; }
    if (t == 0) bbase0[NB] = E;
}

// ---------- partition phase 1: bucket edges, contiguous runs per block ----------
// pairs[pos] = (src << 8) | (dst & 255)
__global__ void __launch_bounds__(256, 4) k_part1(
    const int* __restrict__ ei, int* __restrict__ bcur,
    unsigned* __restrict__ pairs, int E, int NB)
{
    __shared__ int hist[512], bbase[512], bofs[512];
    const int t = threadIdx.x;
    const int e0 = blockIdx.x * 4096;
    for (int i = t; i < NB; i += 256) hist[i] = 0;
    __syncthreads();
    int sv[16], dv[16];
    #pragma unroll
    for (int i = 0; i < 16; ++i) {
        int e = e0 + i * 256 + t;
        if (e < E) {
            sv[i] = ei[e];
            dv[i] = ei[E + e];
            atomicAdd(&hist[dv[i] >> BSHIFT], 1);
        } else dv[i] = -1;
    }
    __syncthreads();
    for (int i = t; i < NB; i += 256) {
        int hcnt = hist[i];
        bbase[i] = hcnt ? atomicAdd(&bcur[i], hcnt) : 0;
        bofs[i] = 0;
    }
    __syncthreads();
    #pragma unroll
    for (int i = 0; i < 16; ++i) {
        if (dv[i] >= 0) {
            int k = dv[i] >> BSHIFT;
            int o = atomicAdd(&bofs[k], 1);
            pairs[bbase[k] + o] = ((unsigned)sv[i] << BSHIFT) | (unsigned)(dv[i] & 255);
        }
    }
}

// ---------- partition phase 2: per bucket, LDS deg + scan + scatter; write rowstart/deg ----------
__global__ void __launch_bounds__(256, 4) k_part2(
    const unsigned* __restrict__ pairs, const int* __restrict__ bbase0,
    int* __restrict__ csr_src, int* __restrict__ rowstart, int* __restrict__ deg, int N)
{
    __shared__ int dcnt[256], sh[256], cur[256];
    const int t = threadIdx.x;
    const int b = blockIdx.x;
    const int start = bbase0[b], end = bbase0[b + 1];
    dcnt[t] = 0;
    __syncthreads();
    for (int i = start + t; i < end; i += 256) atomicAdd(&dcnt[pairs[i] & 255], 1);
    __syncthreads();
    int v = dcnt[t];
    sh[t] = v;
    __syncthreads();
    for (int off = 1; off < 256; off <<= 1) {
        int y = (t >= off) ? sh[t - off] : 0;
        __syncthreads();
        sh[t] += y;
        __syncthreads();
    }
    int rbase = start + sh[t] - v;          // row start of node (b<<8)+t
    int node = (b << BSHIFT) + t;
    if (node < N) { rowstart[node] = rbase; deg[node] = v; }
    cur[t] = rbase;
    __syncthreads();
    for (int i = start + t; i < end; i += 256) {
        unsigned p = pairs[i];
        int pos = atomicAdd(&cur[p & 255], 1);
        csr_src[pos] = (int)(p >> BSHIFT);
    }
}

// ---------- aggregation: 8 lanes/node, 8 bf16 ch/lane (uint4), shfl-broadcast ----------
__global__ void __launch_bounds__(256, 6) k_aggregate(
    const int* __restrict__ csr_src, const int* __restrict__ rowstart,
    const int* __restrict__ deg,
    const float* __restrict__ aS, const float* __restrict__ aD,
    const __hip_bfloat16* __restrict__ hb, const float* __restrict__ conv_b,
    float* __restrict__ hgat, float* __restrict__ bnsum, float* __restrict__ bnsq, int N)
{
    __shared__ float ps[256][8], pq[256][8];
    const int t = threadIdx.x;
    const int g = t & 7;
    const int grp = t >> 3;
    const int lb = (t & 63) & ~7;
    const uint4* hp = (const uint4*)hb;
    float bc[8];
    {
        float4 b0 = ((const float4*)conv_b)[2*g+0];
        float4 b1 = ((const float4*)conv_b)[2*g+1];
        bc[0]=b0.x; bc[1]=b0.y; bc[2]=b0.z; bc[3]=b0.w;
        bc[4]=b1.x; bc[5]=b1.y; bc[6]=b1.z; bc[7]=b1.w;
    }
    float psum[8], psq[8];
    #pragma unroll
    for (int j = 0; j < 8; ++j) { psum[j] = 0.f; psq[j] = 0.f; }
    const int stride = gridDim.x * 32;

    for (int n = blockIdx.x * 32 + grp; n < N; n += stride) {
        const int start = rowstart[n];
        const int end = start + deg[n];
        const float aDn = aD[n];
        const float wself = __expf(lrelu(aS[n] + aDn));
        uint4 hs = hp[(size_t)n * 8 + g];
        float acc[8];
        acc[0] = wself * bflo(hs.x); acc[1] = wself * bfhi(hs.x);
        acc[2] = wself * bflo(hs.y); acc[3] = wself * bfhi(hs.y);
        acc[4] = wself * bflo(hs.z); acc[5] = wself * bfhi(hs.z);
        acc[6] = wself * bflo(hs.w); acc[7] = wself * bfhi(hs.w);
        float wpart = (g == 0) ? wself : 0.f;

        for (int base = start; base < end; base += 8) {
            int cnt = end - base; cnt = cnt > 8 ? 8 : cnt;
            int   s_l = 0;
            float w_l = 0.f;
            if (g < cnt) {
                s_l = csr_src[base + g];
                w_l = __expf(lrelu(aS[s_l] + aDn));
                wpart += w_l;
                s_l <<= 3;
            }
            int j = 0;
            for (; j + 4 <= cnt; j += 4) {
                float w0 = __shfl(w_l, lb+j+0); int s0 = __shfl(s_l, lb+j+0);
                float w1 = __shfl(w_l, lb+j+1); int s1 = __shfl(s_l, lb+j+1);
                float w2 = __shfl(w_l, lb+j+2); int s2 = __shfl(s_l, lb+j+2);
                float w3 = __shfl(w_l, lb+j+3); int s3 = __shfl(s_l, lb+j+3);
                uint4 q0 = hp[s0 + g];
                uint4 q1 = hp[s1 + g];
                uint4 q2 = hp[s2 + g];
                uint4 q3 = hp[s3 + g];
                acc[0]=fmaf(w0,bflo(q0.x),acc[0]); acc[1]=fmaf(w0,bfhi(q0.x),acc[1]);
                acc[2]=fmaf(w0,bflo(q0.y),acc[2]); acc[3]=fmaf(w0,bfhi(q0.y),acc[3]);
                acc[4]=fmaf(w0,bflo(q0.z),acc[4]); acc[5]=fmaf(w0,bfhi(q0.z),acc[5]);
                acc[6]=fmaf(w0,bflo(q0.w),acc[6]); acc[7]=fmaf(w0,bfhi(q0.w),acc[7]);
                acc[0]=fmaf(w1,bflo(q1.x),acc[0]); acc[1]=fmaf(w1,bfhi(q1.x),acc[1]);
                acc[2]=fmaf(w1,bflo(q1.y),acc[2]); acc[3]=fmaf(w1,bfhi(q1.y),acc[3]);
                acc[4]=fmaf(w1,bflo(q1.z),acc[4]); acc[5]=fmaf(w1,bfhi(q1.z),acc[5]);
                acc[6]=fmaf(w1,bflo(q1.w),acc[6]); acc[7]=fmaf(w1,bfhi(q1.w),acc[7]);
                acc[0]=fmaf(w2,bflo(q2.x),acc[0]); acc[1]=fmaf(w2,bfhi(q2.x),acc[1]);
                acc[2]=fmaf(w2,bflo(q2.y),acc[2]); acc[3]=fmaf(w2,bfhi(q2.y),acc[3]);
                acc[4]=fmaf(w2,bflo(q2.z),acc[4]); acc[5]=fmaf(w2,bfhi(q2.z),acc[5]);
                acc[6]=fmaf(w2,bflo(q2.w),acc[6]); acc[7]=fmaf(w2,bfhi(q2.w),acc[7]);
                acc[0]=fmaf(w3,bflo(q3.x),acc[0]); acc[1]=fmaf(w3,bfhi(q3.x),acc[1]);
                acc[2]=fmaf(w3,bflo(q3.y),acc[2]); acc[3]=fmaf(w3,bfhi(q3.y),acc[3]);
                acc[4]=fmaf(w3,bflo(q3.z),acc[4]); acc[5]=fmaf(w3,bfhi(q3.z),acc[5]);
                acc[6]=fmaf(w3,bflo(q3.w),acc[6]); acc[7]=fmaf(w3,bfhi(q3.w),acc[7]);
            }
            for (; j < cnt; ++j) {
                float w0 = __shfl(w_l, lb+j); int s0 = __shfl(s_l, lb+j);
                uint4 q0 = hp[s0 + g];
                acc[0]=fmaf(w0,bflo(q0.x),acc[0]); acc[1]=fmaf(w0,bfhi(q0.x),acc[1]);
                acc[2]=fmaf(w0,bflo(q0.y),acc[2]); acc[3]=fmaf(w0,bfhi(q0.y),acc[3]);
                acc[4]=fmaf(w0,bflo(q0.z),acc[4]); acc[5]=fmaf(w0,bfhi(q0.z),acc[5]);
                acc[6]=fmaf(w0,bflo(q0.w),acc[6]); acc[7]=fmaf(w0,bfhi(q0.w),acc[7]);
            }
        }
        wpart += __shfl_xor(wpart, 1);
        wpart += __shfl_xor(wpart, 2);
        wpart += __shfl_xor(wpart, 4);
        float inv = 1.f / wpart;
        float v[8];
        #pragma unroll
        for (int j = 0; j < 8; ++j) {
            v[j] = fmaf(acc[j], inv, bc[j]);
            psum[j] += v[j];
            psq[j] = fmaf(v[j], v[j], psq[j]);
        }
        float4* op = (float4*)(hgat + (size_t)n * 64 + g * 8);
        op[0] = make_float4(v[0], v[1], v[2], v[3]);
        op[1] = make_float4(v[4], v[5], v[6], v[7]);
    }
    #pragma unroll
    for (int j = 0; j < 8; ++j) { ps[t][j] = psum[j]; pq[t][j] = psq[j]; }
    __syncthreads();
    if (t < 64) {
        int p = t >> 3, j = t & 7;
        float s = 0.f, q = 0.f;
        #pragma unroll
        for (int k = 0; k < 32; ++k) {
            s += ps[k * 8 + p][j];
            q += pq[k * 8 + p][j];
        }
        unsafeAtomicAdd(&bnsum[t], s);
        unsafeAtomicAdd(&bnsq[t], q);
    }
}

// ---------- BN params (per-block) + BN apply + ReLU + FC(64->32) ----------
__global__ void k_bn_fc(const float* __restrict__ hg, const float* __restrict__ bnsum,
                        const float* __restrict__ bnsq, const float* __restrict__ gamma,
                        const float* __restrict__ beta, const float* __restrict__ fcW,
                        const float* __restrict__ fcb, float* __restrict__ out, int N)
{
    __shared__ float Ws[2048];
    __shared__ float sc[64], sh[64];
    const int t = threadIdx.x;
    for (int i = t; i < 2048; i += 256) Ws[i] = fcW[i];
    if (t < 64) {
        float invN = 1.f / (float)N;
        float mu  = bnsum[t] * invN;
        float var = bnsq[t] * invN - mu * mu;
        float s   = gamma[t] * rsqrtf(var + BN_EPS);
        sc[t] = s;
        sh[t] = beta[t] - mu * s;
    }
    __syncthreads();
    int n = blockIdx.x * 256 + t;
    if (n >= N) return;
    float y[64];
    const float4* hp = (const float4*)(hg + (size_t)n * 64);
    #pragma unroll
    for (int i = 0; i < 16; ++i) {
        float4 v = hp[i];
        y[4*i+0] = fmaxf(fmaf(v.x, sc[4*i+0], sh[4*i+0]), 0.f);
        y[4*i+1] = fmaxf(fmaf(v.y, sc[4*i+1], sh[4*i+1]), 0.f);
        y[4*i+2] = fmaxf(fmaf(v.z, sc[4*i+2], sh[4*i+2]), 0.f);
        y[4*i+3] = fmaxf(fmaf(v.w, sc[4*i+3], sh[4*i+3]), 0.f);
    }
    float4* op = (float4*)(out + (size_t)n * 32);
    #pragma unroll
    for (int o4 = 0; o4 < 8; ++o4) {
        float a0 = fcb[4*o4+0], a1 = fcb[4*o4+1], a2 = fcb[4*o4+2], a3 = fcb[4*o4+3];
        #pragma unroll
        for (int k = 0; k < 64; ++k) {
            float yv = y[k];
            a0 = fmaf(yv, Ws[(4*o4+0)*64+k], a0);
            a1 = fmaf(yv, Ws[(4*o4+1)*64+k], a1);
            a2 = fmaf(yv, Ws[(4*o4+2)*64+k], a2);
            a3 = fmaf(yv, Ws[(4*o4+3)*64+k], a3);
        }
        op[o4] = make_float4(a0, a1, a2, a3);
    }
}

// ---------- launch ----------
extern "C" void kernel_launch(void* const* d_in, const int* in_sizes, int n_in,
                              void* d_out, int out_size, void* d_ws, size_t ws_size,
                              hipStream_t stream)
{
    const float* x       = (const float*)d_in[0];
    const int*   ei      = (const int*)d_in[1];
    const float* W       = (const float*)d_in[2];
    const float* att_src = (const float*)d_in[3];
    const float* att_dst = (const float*)d_in[4];
    const float* conv_b  = (const float*)d_in[5];
    const float* gamma   = (const float*)d_in[6];
    const float* beta    = (const float*)d_in[7];
    const float* fcW     = (const float*)d_in[8];
    const float* fcb     = (const float*)d_in[9];

    const int N = in_sizes[0] / 64;
    const int E = in_sizes[1] / 2;
    const int NB = (N + 255) >> BSHIFT;

    // workspace layout
    float* ws = (float*)d_ws;
    size_t N64 = (size_t)N * 64;
    float*    hgat    = ws;                            // N*64 f32
    __hip_bfloat16* hb = (__hip_bfloat16*)(hgat + N64);// N*64 bf16
    float*    aS      = hgat + N64 + N64 / 2;          // N
    float*    aD      = aS + N;                        // N
    float*    bnsum   = aD + N;                        // 64
    float*    bnsq    = bnsum + 64;                    // 64
    int*      rowstart= (int*)(bnsq + 64);             // N
    int*      deg     = rowstart + N;                  // N
    int*      bucketCnt = deg + N;                     // 512
    int*      bcur    = bucketCnt + 512;               // 512
    int*      bbase0  = bcur + 512;                    // 512
    int*      csr_src = bbase0 + 512;                  // E
    unsigned* pairs   = (unsigned*)(csr_src + E);      // E

    hipMemsetAsync(bucketCnt, 0, 512 * sizeof(int), stream);

    k_gemm_h<<<(N + 63) / 64, 256, 0, stream>>>(x, W, att_src, att_dst, ei,
                                                hb, aS, aD, bucketCnt, bnsum, N, E, NB);
    k_bscan<<<1, 512, 0, stream>>>(bucketCnt, bcur, bbase0, NB, E);
    k_part1<<<(E + 4095) / 4096, 256, 0, stream>>>(ei, bcur, pairs, E, NB);
    k_part2<<<NB, 256, 0, stream>>>(pairs, bbase0, csr_src, rowstart, deg, N);

    k_aggregate<<<2048, 256, 0, stream>>>(csr_src, rowstart, deg, aS, aD, hb,
                                          conv_b, hgat, bnsum, bnsq, N);
    k_bn_fc<<<(N + 255) / 256, 256, 0, stream>>>(hgat, bnsum, bnsq, gamma, beta,
                                                 fcW, fcb, (float*)d_out, N);
}

// Round 15
// 332.860 us; speedup vs baseline: 3.2027x; 3.2027x over previous
//
#include <hip/hip_runtime.h>
#include <hip/hip_bf16.h>

#define NEG_SLOPE 0.2f
#define BN_EPS 1e-5f
#define BSHIFT 8            // bucket = 256 dst nodes

__device__ __forceinline__ float lrelu(float x) { return x > 0.f ? x : NEG_SLOPE * x; }
__device__ __forceinline__ float bflo(unsigned u) { return __uint_as_float(u << 16); }
__device__ __forceinline__ float bfhi(unsigned u) { return __uint_as_float(u & 0xffff0000u); }

// ---------- kernel A: hb(bf16) = x@W^T (R13 body: per-node dot, Wreg/L1), LDS bucket-hist ----------
// NOTE (R14 post-mortem): do NOT register-block 16 nodes x unrolled k here — it spills
// acc[] to scratch (2.6 GB traffic, 8x slower). R13's per-node loop stays in budget.
__global__ void __launch_bounds__(256, 4) k_gemm_h(
    const float* __restrict__ x, const float* __restrict__ W,
    const float* __restrict__ att_src, const float* __restrict__ att_dst,
    const int* __restrict__ ei, __hip_bfloat16* __restrict__ hb,
    float* __restrict__ aS, float* __restrict__ aD,
    int* __restrict__ bucketCnt, float* __restrict__ bnzero, int N, int E, int NB)
{
    __shared__ float4 xs[64][17];
    __shared__ int bh[512];
    const int t = threadIdx.x;
    const int c = t & 63;
    const int wv = t >> 6;
    const int n0 = blockIdx.x * 64;

    float Wreg[64];
    const float4* Wp = (const float4*)W;
    #pragma unroll
    for (int k4 = 0; k4 < 16; ++k4) {
        float4 w4 = Wp[c * 16 + k4];
        Wreg[4*k4+0] = w4.x; Wreg[4*k4+1] = w4.y;
        Wreg[4*k4+2] = w4.z; Wreg[4*k4+3] = w4.w;
    }
    const float4* xp = (const float4*)x;
    #pragma unroll
    for (int i = 0; i < 4; ++i) {
        int idx = i * 256 + t;
        int row = idx >> 4, k4 = idx & 15;
        xs[row][k4] = (n0 + row < N) ? xp[(size_t)n0 * 16 + idx] : make_float4(0,0,0,0);
    }
    for (int i = t; i < NB; i += 256) bh[i] = 0;
    __syncthreads();

    const float asc = att_src[c], adc = att_dst[c];
    for (int i = 0; i < 16; ++i) {
        int nl = wv * 16 + i;
        int n = n0 + nl;
        if (n >= N) break;
        float a = 0.f;
        #pragma unroll
        for (int k4 = 0; k4 < 16; ++k4) {
            float4 xv = xs[nl][k4];
            a = fmaf(xv.x, Wreg[4*k4+0], a);
            a = fmaf(xv.y, Wreg[4*k4+1], a);
            a = fmaf(xv.z, Wreg[4*k4+2], a);
            a = fmaf(xv.w, Wreg[4*k4+3], a);
        }
        hb[(size_t)n * 64 + c] = __float2bfloat16(a);
        float s = a * asc, d = a * adc;
        #pragma unroll
        for (int off = 32; off; off >>= 1) { s += __shfl_xor(s, off); d += __shfl_xor(d, off); }
        if (c == 0) { aS[n] = s; aD[n] = d; }
    }
    // bucket histogram (LDS-privatized; one global atomic per block,bucket)
    int per = (E + gridDim.x - 1) / gridDim.x;
    int e0 = blockIdx.x * per;
    int e1 = min(e0 + per, E);
    for (int e = e0 + t; e < e1; e += 256) atomicAdd(&bh[ei[E + e] >> BSHIFT], 1);
    __syncthreads();
    for (int i = t; i < NB; i += 256) if (bh[i]) atomicAdd(&bucketCnt[i], bh[i]);
    if (blockIdx.x == 0 && t < 128) bnzero[t] = 0.f;
}

// ---------- bucket scan (NB<=512 values, one block) ----------
__global__ void k_bscan(const int* __restrict__ bucketCnt, int* __restrict__ bcur,
                        int* __restrict__ bbase0, int NB, int E)
{
    __shared__ int sh[512];
    const int t = threadIdx.x;
    int v = (t < NB) ? bucketCnt[t] : 0;
    sh[t] = v;
    __syncthreads();
    for (int off = 1; off < 512; off <<= 1) {
        int y = (t >= off) ? sh[t - off] : 0;
        __syncthreads();
        sh[t] += y;
        __syncthreads();
    }
    if (t < NB) { int ex = sh[t] - v; bcur[t] = ex; bbase0[t] = ex; }
    if (t == 0) bbase0[NB] = E;
}

// ---------- partition phase 1: bucket edges, contiguous runs per block ----------
// pairs[pos] = (src << 8) | (dst & 255)
__global__ void __launch_bounds__(256, 4) k_part1(
    const int* __restrict__ ei, int* __restrict__ bcur,
    unsigned* __restrict__ pairs, int E, int NB)
{
    __shared__ int hist[512], bbase[512], bofs[512];
    const int t = threadIdx.x;
    const int e0 = blockIdx.x * 4096;
    for (int i = t; i < NB; i += 256) hist[i] = 0;
    __syncthreads();
    int sv[16], dv[16];
    #pragma unroll
    for (int i = 0; i < 16; ++i) {
        int e = e0 + i * 256 + t;
        if (e < E) {
            sv[i] = ei[e];
            dv[i] = ei[E + e];
            atomicAdd(&hist[dv[i] >> BSHIFT], 1);
        } else dv[i] = -1;
    }
    __syncthreads();
    for (int i = t; i < NB; i += 256) {
        int hcnt = hist[i];
        bbase[i] = hcnt ? atomicAdd(&bcur[i], hcnt) : 0;
        bofs[i] = 0;
    }
    __syncthreads();
    #pragma unroll
    for (int i = 0; i < 16; ++i) {
        if (dv[i] >= 0) {
            int k = dv[i] >> BSHIFT;
            int o = atomicAdd(&bofs[k], 1);
            pairs[bbase[k] + o] = ((unsigned)sv[i] << BSHIFT) | (unsigned)(dv[i] & 255);
        }
    }
}

// ---------- partition phase 2: per bucket, LDS deg + scan + scatter; write rowstart/deg ----------
__global__ void __launch_bounds__(256, 4) k_part2(
    const unsigned* __restrict__ pairs, const int* __restrict__ bbase0,
    int* __restrict__ csr_src, int* __restrict__ rowstart, int* __restrict__ deg, int N)
{
    __shared__ int dcnt[256], sh[256], cur[256];
    const int t = threadIdx.x;
    const int b = blockIdx.x;
    const int start = bbase0[b], end = bbase0[b + 1];
    dcnt[t] = 0;
    __syncthreads();
    for (int i = start + t; i < end; i += 256) atomicAdd(&dcnt[pairs[i] & 255], 1);
    __syncthreads();
    int v = dcnt[t];
    sh[t] = v;
    __syncthreads();
    for (int off = 1; off < 256; off <<= 1) {
        int y = (t >= off) ? sh[t - off] : 0;
        __syncthreads();
        sh[t] += y;
        __syncthreads();
    }
    int rbase = start + sh[t] - v;          // row start of node (b<<8)+t
    int node = (b << BSHIFT) + t;
    if (node < N) { rowstart[node] = rbase; deg[node] = v; }
    cur[t] = rbase;
    __syncthreads();
    for (int i = start + t; i < end; i += 256) {
        unsigned p = pairs[i];
        int pos = atomicAdd(&cur[p & 255], 1);
        csr_src[pos] = (int)(p >> BSHIFT);
    }
}

// ---------- aggregation: 8 lanes/node, 8 bf16 ch/lane (uint4), shfl-broadcast ----------
__global__ void __launch_bounds__(256, 6) k_aggregate(
    const int* __restrict__ csr_src, const int* __restrict__ rowstart,
    const int* __restrict__ deg,
    const float* __restrict__ aS, const float* __restrict__ aD,
    const __hip_bfloat16* __restrict__ hb, const float* __restrict__ conv_b,
    float* __restrict__ hgat, float* __restrict__ bnsum, float* __restrict__ bnsq, int N)
{
    __shared__ float ps[256][8], pq[256][8];
    const int t = threadIdx.x;
    const int g = t & 7;
    const int grp = t >> 3;
    const int lb = (t & 63) & ~7;
    const uint4* hp = (const uint4*)hb;
    float bc[8];
    {
        float4 b0 = ((const float4*)conv_b)[2*g+0];
        float4 b1 = ((const float4*)conv_b)[2*g+1];
        bc[0]=b0.x; bc[1]=b0.y; bc[2]=b0.z; bc[3]=b0.w;
        bc[4]=b1.x; bc[5]=b1.y; bc[6]=b1.z; bc[7]=b1.w;
    }
    float psum[8], psq[8];
    #pragma unroll
    for (int j = 0; j < 8; ++j) { psum[j] = 0.f; psq[j] = 0.f; }
    const int stride = gridDim.x * 32;

    for (int n = blockIdx.x * 32 + grp; n < N; n += stride) {
        const int start = rowstart[n];
        const int end = start + deg[n];
        const float aDn = aD[n];
        const float wself = __expf(lrelu(aS[n] + aDn));
        uint4 hs = hp[(size_t)n * 8 + g];
        float acc[8];
        acc[0] = wself * bflo(hs.x); acc[1] = wself * bfhi(hs.x);
        acc[2] = wself * bflo(hs.y); acc[3] = wself * bfhi(hs.y);
        acc[4] = wself * bflo(hs.z); acc[5] = wself * bfhi(hs.z);
        acc[6] = wself * bflo(hs.w); acc[7] = wself * bfhi(hs.w);
        float wpart = (g == 0) ? wself : 0.f;

        for (int base = start; base < end; base += 8) {
            int cnt = end - base; cnt = cnt > 8 ? 8 : cnt;
            int   s_l = 0;
            float w_l = 0.f;
            if (g < cnt) {
                s_l = csr_src[base + g];
                w_l = __expf(lrelu(aS[s_l] + aDn));
                wpart += w_l;
                s_l <<= 3;
            }
            int j = 0;
            for (; j + 4 <= cnt; j += 4) {
                float w0 = __shfl(w_l, lb+j+0); int s0 = __shfl(s_l, lb+j+0);
                float w1 = __shfl(w_l, lb+j+1); int s1 = __shfl(s_l, lb+j+1);
                float w2 = __shfl(w_l, lb+j+2); int s2 = __shfl(s_l, lb+j+2);
                float w3 = __shfl(w_l, lb+j+3); int s3 = __shfl(s_l, lb+j+3);
                uint4 q0 = hp[s0 + g];
                uint4 q1 = hp[s1 + g];
                uint4 q2 = hp[s2 + g];
                uint4 q3 = hp[s3 + g];
                acc[0]=fmaf(w0,bflo(q0.x),acc[0]); acc[1]=fmaf(w0,bfhi(q0.x),acc[1]);
                acc[2]=fmaf(w0,bflo(q0.y),acc[2]); acc[3]=fmaf(w0,bfhi(q0.y),acc[3]);
                acc[4]=fmaf(w0,bflo(q0.z),acc[4]); acc[5]=fmaf(w0,bfhi(q0.z),acc[5]);
                acc[6]=fmaf(w0,bflo(q0.w),acc[6]); acc[7]=fmaf(w0,bfhi(q0.w),acc[7]);
                acc[0]=fmaf(w1,bflo(q1.x),acc[0]); acc[1]=fmaf(w1,bfhi(q1.x),acc[1]);
                acc[2]=fmaf(w1,bflo(q1.y),acc[2]); acc[3]=fmaf(w1,bfhi(q1.y),acc[3]);
                acc[4]=fmaf(w1,bflo(q1.z),acc[4]); acc[5]=fmaf(w1,bfhi(q1.z),acc[5]);
                acc[6]=fmaf(w1,bflo(q1.w),acc[6]); acc[7]=fmaf(w1,bfhi(q1.w),acc[7]);
                acc[0]=fmaf(w2,bflo(q2.x),acc[0]); acc[1]=fmaf(w2,bfhi(q2.x),acc[1]);
                acc[2]=fmaf(w2,bflo(q2.y),acc[2]); acc[3]=fmaf(w2,bfhi(q2.y),acc[3]);
                acc[4]=fmaf(w2,bflo(q2.z),acc[4]); acc[5]=fmaf(w2,bfhi(q2.z),acc[5]);
                acc[6]=fmaf(w2,bflo(q2.w),acc[6]); acc[7]=fmaf(w2,bfhi(q2.w),acc[7]);
                acc[0]=fmaf(w3,bflo(q3.x),acc[0]); acc[1]=fmaf(w3,bfhi(q3.x),acc[1]);
                acc[2]=fmaf(w3,bflo(q3.y),acc[2]); acc[3]=fmaf(w3,bfhi(q3.y),acc[3]);
                acc[4]=fmaf(w3,bflo(q3.z),acc[4]); acc[5]=fmaf(w3,bfhi(q3.z),acc[5]);
                acc[6]=fmaf(w3,bflo(q3.w),acc[6]); acc[7]=fmaf(w3,bfhi(q3.w),acc[7]);
            }
            for (; j < cnt; ++j) {
                float w0 = __shfl(w_l, lb+j); int s0 = __shfl(s_l, lb+j);
                uint4 q0 = hp[s0 + g];
                acc[0]=fmaf(w0,bflo(q0.x),acc[0]); acc[1]=fmaf(w0,bfhi(q0.x),acc[1]);
                acc[2]=fmaf(w0,bflo(q0.y),acc[2]); acc[3]=fmaf(w0,bfhi(q0.y),acc[3]);
                acc[4]=fmaf(w0,bflo(q0.z),acc[4]); acc[5]=fmaf(w0,bfhi(q0.z),acc[5]);
                acc[6]=fmaf(w0,bflo(q0.w),acc[6]); acc[7]=fmaf(w0,bfhi(q0.w),acc[7]);
            }
        }
        wpart += __shfl_xor(wpart, 1);
        wpart += __shfl_xor(wpart, 2);
        wpart += __shfl_xor(wpart, 4);
        float inv = 1.f / wpart;
        float v[8];
        #pragma unroll
        for (int j = 0; j < 8; ++j) {
            v[j] = fmaf(acc[j], inv, bc[j]);
            psum[j] += v[j];
            psq[j] = fmaf(v[j], v[j], psq[j]);
        }
        float4* op = (float4*)(hgat + (size_t)n * 64 + g * 8);
        op[0] = make_float4(v[0], v[1], v[2], v[3]);
        op[1] = make_float4(v[4], v[5], v[6], v[7]);
    }
    #pragma unroll
    for (int j = 0; j < 8; ++j) { ps[t][j] = psum[j]; pq[t][j] = psq[j]; }
    __syncthreads();
    if (t < 64) {
        int p = t >> 3, j = t & 7;
        float s = 0.f, q = 0.f;
        #pragma unroll
        for (int k = 0; k < 32; ++k) {
            s += ps[k * 8 + p][j];
            q += pq[k * 8 + p][j];
        }
        unsafeAtomicAdd(&bnsum[t], s);
        unsafeAtomicAdd(&bnsq[t], q);
    }
}

// ---------- BN params (per-block) + BN apply + ReLU + FC(64->32) ----------
__global__ void k_bn_fc(const float* __restrict__ hg, const float* __restrict__ bnsum,
                        const float* __restrict__ bnsq, const float* __restrict__ gamma,
                        const float* __restrict__ beta, const float* __restrict__ fcW,
                        const float* __restrict__ fcb, float* __restrict__ out, int N)
{
    __shared__ float Ws[2048];
    __shared__ float sc[64], sh[64];
    const int t = threadIdx.x;
    for (int i = t; i < 2048; i += 256) Ws[i] = fcW[i];
    if (t < 64) {
        float invN = 1.f / (float)N;
        float mu  = bnsum[t] * invN;
        float var = bnsq[t] * invN - mu * mu;
        float s   = gamma[t] * rsqrtf(var + BN_EPS);
        sc[t] = s;
        sh[t] = beta[t] - mu * s;
    }
    __syncthreads();
    int n = blockIdx.x * 256 + t;
    if (n >= N) return;
    float y[64];
    const float4* hp = (const float4*)(hg + (size_t)n * 64);
    #pragma unroll
    for (int i = 0; i < 16; ++i) {
        float4 v = hp[i];
        y[4*i+0] = fmaxf(fmaf(v.x, sc[4*i+0], sh[4*i+0]), 0.f);
        y[4*i+1] = fmaxf(fmaf(v.y, sc[4*i+1], sh[4*i+1]), 0.f);
        y[4*i+2] = fmaxf(fmaf(v.z, sc[4*i+2], sh[4*i+2]), 0.f);
        y[4*i+3] = fmaxf(fmaf(v.w, sc[4*i+3], sh[4*i+3]), 0.f);
    }
    float4* op = (float4*)(out + (size_t)n * 32);
    #pragma unroll
    for (int o4 = 0; o4 < 8; ++o4) {
        float a0 = fcb[4*o4+0], a1 = fcb[4*o4+1], a2 = fcb[4*o4+2], a3 = fcb[4*o4+3];
        #pragma unroll
        for (int k = 0; k < 64; ++k) {
            float yv = y[k];
            a0 = fmaf(yv, Ws[(4*o4+0)*64+k], a0);
            a1 = fmaf(yv, Ws[(4*o4+1)*64+k], a1);
            a2 = fmaf(yv, Ws[(4*o4+2)*64+k], a2);
            a3 = fmaf(yv, Ws[(4*o4+3)*64+k], a3);
        }
        op[o4] = make_float4(a0, a1, a2, a3);
    }
}

// ---------- launch ----------
extern "C" void kernel_launch(void* const* d_in, const int* in_sizes, int n_in,
                              void* d_out, int out_size, void* d_ws, size_t ws_size,
                              hipStream_t stream)
{
    const float* x       = (const float*)d_in[0];
    const int*   ei      = (const int*)d_in[1];
    const float* W       = (const float*)d_in[2];
    const float* att_src = (const float*)d_in[3];
    const float* att_dst = (const float*)d_in[4];
    const float* conv_b  = (const float*)d_in[5];
    const float* gamma   = (const float*)d_in[6];
    const float* beta    = (const float*)d_in[7];
    const float* fcW     = (const float*)d_in[8];
    const float* fcb     = (const float*)d_in[9];

    const int N = in_sizes[0] / 64;
    const int E = in_sizes[1] / 2;
    const int NB = (N + 255) >> BSHIFT;

    // workspace layout
    float* ws = (float*)d_ws;
    size_t N64 = (size_t)N * 64;
    float*    hgat    = ws;                            // N*64 f32
    __hip_bfloat16* hb = (__hip_bfloat16*)(hgat + N64);// N*64 bf16
    float*    aS      = hgat + N64 + N64 / 2;          // N
    float*    aD      = aS + N;                        // N
    float*    bnsum   = aD + N;                        // 64
    float*    bnsq    = bnsum + 64;                    // 64
    int*      rowstart= (int*)(bnsq + 64);             // N
    int*      deg     = rowstart + N;                  // N
    int*      bucketCnt = deg + N;                     // 512
    int*      bcur    = bucketCnt + 512;               // 512
    int*      bbase0  = bcur + 512;                    // 512
    int*      csr_src = bbase0 + 512;                  // E
    unsigned* pairs   = (unsigned*)(csr_src + E);      // E

    hipMemsetAsync(bucketCnt, 0, 512 * sizeof(int), stream);

    k_gemm_h<<<(N + 63) / 64, 256, 0, stream>>>(x, W, att_src, att_dst, ei,
                                                hb, aS, aD, bucketCnt, bnsum, N, E, NB);
    k_bscan<<<1, 512, 0, stream>>>(bucketCnt, bcur, bbase0, NB, E);
    k_part1<<<(E + 4095) / 4096, 256, 0, stream>>>(ei, bcur, pairs, E, NB);
    k_part2<<<NB, 256, 0, stream>>>(pairs, bbase0, csr_src, rowstart, deg, N);

    k_aggregate<<<2048, 256, 0, stream>>>(csr_src, rowstart, deg, aS, aD, hb,
                                          conv_b, hgat, bnsum, bnsq, N);
    k_bn_fc<<<(N + 255) / 256, 256, 0, stream>>>(hgat, bnsum, bnsq, gamma, beta,
                                                 fcW, fcb, (float*)d_out, N);
}